// Round 12
// baseline (115.892 us; speedup 1.0000x reference)
//
#include <hip/hip_runtime.h>
#include <math.h>

// VectorQuantizer on MI355X — R22 == R21 resubmit (infra container failure,
// kernel never ran; source re-audited, unchanged).
// R21: coalesced X-load + LDS transpose.
// R20 null (5th): staging-hoist/occupancy/writes/final all falsified; scan
// ~40 µs with pipes idle in every structure. The ONE invariant: X loaded as
// 32 scalar dwords/thread at 16 KB stride — 4 disjoint 64B lines per wave-
// instr (256B useful vs 1KB), 4x VMEM instrs, cold sector-gathers every
// iteration (the 256 MiB ws-poison evicts L3). R21: per iter one wave loads
// ONE channel row contiguously (float4, 1KB/wave-instr, 8 instrs in flight),
// f2bf(-2x) -> xh[64][260] u16 LDS (b64 writes conflict-free; pad 260 makes
// one-time fragment reads ~2-4-way), fragments from LDS. X VMEM instrs 32->8.
// wpack (R20), epilogue, final_p unchanged. 2 barriers. LDS ~38.5KB -> 4/CU.
// Lessons: no nontemporal (R12), no cross-block fences (R12/R13/R18), no
// fusion, plain cached epilogue stores.
// ws: [0,64K) wpack u16 | [64K,66K) wsqf f32[512]
//     | [66K,+512K) pcounts u16[512][512] | +4K ssep f64[512]

#define NTOK 131072
#define KCODES 512
#define HW 4096
#define CHW 262144
#define NELEM 8388608
#define XPAD 260

typedef __attribute__((ext_vector_type(8))) short short8;
typedef __attribute__((ext_vector_type(4))) float f32x4;
typedef __attribute__((ext_vector_type(4))) unsigned short u16x4;

static __device__ __forceinline__ unsigned short f2bf(float f) {
    unsigned u = __float_as_uint(f);
    unsigned r = u + 0x7FFFu + ((u >> 16) & 1u);  // RNE
    return (unsigned short)(r >> 16);
}

// one-shot: pack codebook into MFMA B-fragment order + compute seeds.
__global__ __launch_bounds__(512) void vq_pack(const float* __restrict__ w,
                                               unsigned short* __restrict__ wpack,
                                               float* __restrict__ wsqf) {
    const int code = threadIdx.x;               // 512 threads, 1 block
    const int tt = code >> 4, cc = code & 15;
    const float4* src = (const float4*)(w + code * 64);
    float4 v[16];
#pragma unroll
    for (int i = 0; i < 16; ++i) v[i] = src[i];
    float s = 0.f;
#pragma unroll
    for (int i = 0; i < 16; ++i) {
        s = fmaf(v[i].x, v[i].x, s); s = fmaf(v[i].y, v[i].y, s);
        s = fmaf(v[i].z, v[i].z, s); s = fmaf(v[i].w, v[i].w, s);
    }
    wsqf[code] = 1.25f + s;
#pragma unroll
    for (int ch = 0; ch < 2; ++ch)
#pragma unroll
        for (int qd = 0; qd < 4; ++qd) {
            const int g = tt * 128 + ch * 64 + qd * 16 + cc;
            const int e0 = ch * 8 + qd * 2;
            const float4 a = v[e0], b = v[e0 + 1];
            short8 hv;
            hv[0] = (short)f2bf(a.x); hv[1] = (short)f2bf(a.y);
            hv[2] = (short)f2bf(a.z); hv[3] = (short)f2bf(a.w);
            hv[4] = (short)f2bf(b.x); hv[5] = (short)f2bf(b.y);
            hv[6] = (short)f2bf(b.z); hv[7] = (short)f2bf(b.w);
            *(short8*)(wpack + g * 8) = hv;
        }
}

__global__ __launch_bounds__(512, 4) void vq_scan(const float* __restrict__ in,
                                                  const float* __restrict__ w,
                                                  const unsigned short* __restrict__ wpack,
                                                  const float* __restrict__ wsqf,
                                                  float* __restrict__ out,
                                                  unsigned short* __restrict__ pcounts,
                                                  double* __restrict__ ssep,
                                                  float* __restrict__ counts,
                                                  double* __restrict__ sse_acc,
                                                  const int amode) {
    __shared__ __align__(16) unsigned short xh[64][XPAD];  // 33280 B bf16(-2x)
    __shared__ float wsqp[KCODES];              // 2048 B seeds
    __shared__ int idxbuf[256];                 // 1024 B
    __shared__ int hist[KCODES];                // 2048 B
    __shared__ double sred[8];

    const int tid = threadIdx.x;
    const int lane = tid & 63, wv = tid >> 6;   // wv in [0,8)
    const int col = lane & 15, quad = lane >> 4;
    const int ntok0 = blockIdx.x * 256;         // 512 blocks x 256 tokens

    wsqp[tid] = wsqf[tid];
    hist[tid] = 0;

    // ---- coalesced X load: wave wv, iter i -> channel c = i*8+wv, whole
    // 256-token row as float4 (lane*4..+3). 1KB/wave-instr, 8 in flight. ----
    const float* ibase = in + (ntok0 >> 12) * CHW + (ntok0 & 4095);
    float4 xv[8];
#pragma unroll
    for (int i = 0; i < 8; ++i)
        xv[i] = *(const float4*)(ibase + (i * 8 + wv) * HW + lane * 4);

    float xsq = 0.f;
#pragma unroll
    for (int i = 0; i < 8; ++i) {
        const float4 v = xv[i];
        xsq = fmaf(v.x, v.x, xsq); xsq = fmaf(v.y, v.y, xsq);
        xsq = fmaf(v.z, v.z, xsq); xsq = fmaf(v.w, v.w, xsq);
        u16x4 hv;
        hv[0] = f2bf(-2.0f * v.x); hv[1] = f2bf(-2.0f * v.y);
        hv[2] = f2bf(-2.0f * v.z); hv[3] = f2bf(-2.0f * v.w);
        *(u16x4*)(&xh[i * 8 + wv][lane * 4]) = hv;  // b64, conflict-free
    }
    __syncthreads();  // B1: xh + wsqp + hist ready

    // ---- fragment build from LDS (one-time, 64 u16 reads/thread) ----
    short8 ah[2][2];
    {
        const int tok = wv * 32 + col;
#pragma unroll
        for (int sub = 0; sub < 2; ++sub)
#pragma unroll
            for (int cc = 0; cc < 2; ++cc)
#pragma unroll
                for (int j = 0; j < 8; ++j)
                    ah[sub][cc][j] =
                        (short)xh[cc * 32 + quad * 8 + j][tok + sub * 16];
    }

    // ---- scan 32 tiles; B-fragments straight from global (L2-hot) ----
    const unsigned short* pb = wpack + quad * 128 + col * 8;
    unsigned runkey[2][4];
#pragma unroll
    for (int sub = 0; sub < 2; ++sub)
#pragma unroll
        for (int r = 0; r < 4; ++r) runkey[sub][r] = 0xFFFFFFFFu;

#pragma unroll 4
    for (int t = 0; t < 32; ++t) {
        const short8 b0 = *(const short8*)(pb + t * 1024);
        const short8 b1 = *(const short8*)(pb + t * 1024 + 512);
        const int code = t * 16 + col;
        const float seed = wsqp[code];
#pragma unroll
        for (int sub = 0; sub < 2; ++sub) {
            f32x4 acc = {seed, seed, seed, seed};
            acc = __builtin_amdgcn_mfma_f32_16x16x32_bf16(ah[sub][0], b0, acc, 0, 0, 0);
            acc = __builtin_amdgcn_mfma_f32_16x16x32_bf16(ah[sub][1], b1, acc, 0, 0, 0);
#pragma unroll
            for (int r = 0; r < 4; ++r) {
                const unsigned key = (__float_as_uint(acc[r]) << 9) | code;
                runkey[sub][r] = key < runkey[sub][r] ? key : runkey[sub][r];
            }
        }
    }

    // ---- cross-lane argmin over the 16 code-cols ----
#pragma unroll
    for (int s = 1; s < 16; s <<= 1)
#pragma unroll
        for (int sub = 0; sub < 2; ++sub)
#pragma unroll
            for (int r = 0; r < 4; ++r) {
                const unsigned o = __shfl_xor(runkey[sub][r], s, 64);
                runkey[sub][r] = o < runkey[sub][r] ? o : runkey[sub][r];
            }

    // d_best (exact from key) + publish indices (wave-local consumers)
    float dsum = 0.f;
    if (col == 0) {
#pragma unroll
        for (int sub = 0; sub < 2; ++sub)
#pragma unroll
            for (int r = 0; r < 4; ++r) {
                const unsigned key = runkey[sub][r];
                idxbuf[wv * 32 + sub * 16 + quad * 4 + r] = (int)(key & 511u);
                dsum += __uint_as_float((key >> 9) | 0x3F800000u) - 1.25f;
            }
    }
    float contrib = xsq + dsum;
#pragma unroll
    for (int off = 32; off > 0; off >>= 1) contrib += __shfl_down(contrib, off, 64);
    if (lane == 0) sred[wv] = (double)contrib;

    // per-wave histogram over wave-local idxbuf (no barrier needed)
    if (lane < 32) atomicAdd(&hist[idxbuf[wv * 32 + lane]], 1);

    // ---- epilogue: out = w rows (L2-hot); 4 lanes/token, 2 passes ----
#pragma unroll
    for (int p = 0; p < 2; ++p) {
        const int tl = p * 16 + (lane >> 2), q = lane & 3;
        const int n = ntok0 + wv * 32 + tl;
        const int bidx = idxbuf[wv * 32 + tl];
        const float4* wr = (const float4*)(w + bidx * 64 + q * 16);
        float4* op = (float4*)(out + n * 64 + q * 16);
#pragma unroll
        for (int i = 0; i < 4; ++i) op[i] = wr[i];
    }
    __syncthreads();  // B2: hist + sred complete

    if (!amode) {
        pcounts[(blockIdx.x << 9) + tid] = (unsigned short)hist[tid];
        if (tid == 0) {
            double s = sred[0];
#pragma unroll
            for (int i = 1; i < 8; ++i) s += sred[i];
            ssep[blockIdx.x] = s;
        }
    } else {  // fallback: atomics into tiny ws
        const int h = hist[tid];
        if (h) atomicAdd(&counts[tid], (float)h);
        if (tid == 0) {
            double s = sred[0];
#pragma unroll
            for (int i = 1; i < 8; ++i) s += sred[i];
            atomicAdd(sse_acc, s);
        }
    }
}

// parallel reduce: thread t owns 4 codes x 1 block-quarter; u16x4 coalesced
__global__ __launch_bounds__(512) void vq_final_p(const unsigned short* __restrict__ pcounts,
                                                  const double* __restrict__ ssep,
                                                  float* __restrict__ out) {
    __shared__ float part[4][512];   // 8 KB: quarter x code
    __shared__ double red[512];
    __shared__ double sred[512];
    const int t = threadIdx.x;
    const int q = t >> 7, c4 = (t & 127) << 2;

    const u16x4* base = (const u16x4*)pcounts + (q << 14) + (c4 >> 2);
    float4 s = {0.f, 0.f, 0.f, 0.f};
#pragma unroll 16
    for (int b = 0; b < 128; ++b) {        // rows q*128 .. q*128+128
        const u16x4 v = base[b << 7];      // stride 512 ushorts = 128 u16x4
        s.x += (float)v[0]; s.y += (float)v[1];
        s.z += (float)v[2]; s.w += (float)v[3];
    }
    *(float4*)&part[q][c4] = s;
    sred[t] = ssep[t];
    __syncthreads();

    const float cnt = part[0][t] + part[1][t] + part[2][t] + part[3][t];
    const double p = (double)cnt / (double)NTOK;
    red[t] = p * log(p + 1e-10);
    __syncthreads();
#pragma unroll
    for (int st = 256; st > 0; st >>= 1) {
        if (t < st) { red[t] += red[t + st]; sred[t] += sred[t + st]; }
        __syncthreads();
    }
    if (t == 0) {
        out[NELEM] = (float)((sred[0] / (double)NELEM) * 1.25);
        out[NELEM + 1] = (float)exp(-red[0]);
    }
}

__global__ __launch_bounds__(512) void vq_final_a(const float* __restrict__ counts,
                                                  const double* __restrict__ sse_acc,
                                                  float* __restrict__ out) {
    __shared__ double red[512];
    const int k = threadIdx.x;
    const double p = (double)counts[k] / (double)NTOK;
    red[k] = p * log(p + 1e-10);
    __syncthreads();
#pragma unroll
    for (int st = 256; st > 0; st >>= 1) {
        if (k < st) red[k] += red[k + st];
        __syncthreads();
    }
    if (k == 0) {
        out[NELEM] = (float)((*sse_acc / (double)NELEM) * 1.25);
        out[NELEM + 1] = (float)exp(-red[0]);
    }
}

extern "C" void kernel_launch(void* const* d_in, const int* in_sizes, int n_in,
                              void* d_out, int out_size, void* d_ws, size_t ws_size,
                              hipStream_t stream) {
    const float* in = (const float*)d_in[0];
    const float* w = (const float*)d_in[1];
    float* out = (float*)d_out;
    char* ws = (char*)d_ws;

    const size_t WP = 0;                          // 64 KB wpack
    const size_t WQ = 65536;                      // +2 KB wsqf
    const size_t PC = WQ + 2048;                  // +512 KB pcounts u16
    const size_t SSo = PC + (size_t)512 * 512 * 2;  // +4 KB ssep
    const size_t need_full = SSo + 512 * 8;
    const size_t need_min = PC + 2048 + 8;        // counts + sse_acc

    unsigned short* wpack = (unsigned short*)(ws + WP);
    float* wsqf = (float*)(ws + WQ);

    if (ws_size >= need_full) {
        unsigned short* pcounts = (unsigned short*)(ws + PC);
        double* ssep = (double*)(ws + SSo);
        vq_pack<<<1, 512, 0, stream>>>(w, wpack, wsqf);
        vq_scan<<<512, 512, 0, stream>>>(in, w, wpack, wsqf, out, pcounts, ssep,
                                         nullptr, nullptr, 0);
        vq_final_p<<<1, 512, 0, stream>>>(pcounts, ssep, out);
    } else if (ws_size >= need_min) {  // fallback: atomic finals
        float* counts = (float*)(ws + PC);
        double* sse_acc = (double*)(ws + PC + 2048);
        (void)hipMemsetAsync(ws + PC, 0, 2056, stream);
        vq_pack<<<1, 512, 0, stream>>>(w, wpack, wsqf);
        vq_scan<<<512, 512, 0, stream>>>(in, w, wpack, wsqf, out, nullptr, nullptr,
                                         counts, sse_acc, 1);
        vq_final_a<<<1, 512, 0, stream>>>(counts, sse_acc, out);
    }
}

// Round 13
// 113.964 us; speedup vs baseline: 1.0169x; 1.0169x over previous
//
#include <hip/hip_runtime.h>
#include <math.h>

// VectorQuantizer on MI355X — R23: deepen token-blocking (4 subs/wave).
// Six nulls (R14..R22) falsified occupancy/staging/writes/final/X-pattern.
// Scan ~40 µs vs ~15-20 sum-of-parts. Biggest remaining term: B-fragment
// L2 traffic — each wave reads 64 KB wpack/scan amortized over only 32
// tokens (256 MB chip-wide = 7.4 µs). R23: 4 subs/wave = 64 tokens/wave,
// 256 blocks x 512 tokens -> B-traffic/token halved, per-block fixed costs
// halved. Global wpack (R20), scalar X gather (proven line-efficient),
// LDS ~6.3 KB. runkey[4][4], 8 MFMA/tile/wave.
// Pre-commit: |delta| <= 2 µs => structural ceiling, declare next round.
// Lessons: no nontemporal (R12), no cross-block fences (R12/R13/R18), no
// fusion, plain cached epilogue stores.
// ws: [0,64K) wpack u16 | [64K,66K) wsqf f32[512]
//     | [66K,+256K) pcounts u16[256][512] | +2K ssep f64[256]

#define NTOK 131072
#define KCODES 512
#define HW 4096
#define CHW 262144
#define NELEM 8388608

typedef __attribute__((ext_vector_type(8))) short short8;
typedef __attribute__((ext_vector_type(4))) float f32x4;
typedef __attribute__((ext_vector_type(4))) unsigned short u16x4;

static __device__ __forceinline__ unsigned short f2bf(float f) {
    unsigned u = __float_as_uint(f);
    unsigned r = u + 0x7FFFu + ((u >> 16) & 1u);  // RNE
    return (unsigned short)(r >> 16);
}

// one-shot: pack codebook into MFMA B-fragment order + compute seeds.
__global__ __launch_bounds__(512) void vq_pack(const float* __restrict__ w,
                                               unsigned short* __restrict__ wpack,
                                               float* __restrict__ wsqf) {
    const int code = threadIdx.x;               // 512 threads, 1 block
    const int tt = code >> 4, cc = code & 15;
    const float4* src = (const float4*)(w + code * 64);
    float4 v[16];
#pragma unroll
    for (int i = 0; i < 16; ++i) v[i] = src[i];
    float s = 0.f;
#pragma unroll
    for (int i = 0; i < 16; ++i) {
        s = fmaf(v[i].x, v[i].x, s); s = fmaf(v[i].y, v[i].y, s);
        s = fmaf(v[i].z, v[i].z, s); s = fmaf(v[i].w, v[i].w, s);
    }
    wsqf[code] = 1.25f + s;
#pragma unroll
    for (int ch = 0; ch < 2; ++ch)
#pragma unroll
        for (int qd = 0; qd < 4; ++qd) {
            const int g = tt * 128 + ch * 64 + qd * 16 + cc;
            const int e0 = ch * 8 + qd * 2;
            const float4 a = v[e0], b = v[e0 + 1];
            short8 hv;
            hv[0] = (short)f2bf(a.x); hv[1] = (short)f2bf(a.y);
            hv[2] = (short)f2bf(a.z); hv[3] = (short)f2bf(a.w);
            hv[4] = (short)f2bf(b.x); hv[5] = (short)f2bf(b.y);
            hv[6] = (short)f2bf(b.z); hv[7] = (short)f2bf(b.w);
            *(short8*)(wpack + g * 8) = hv;
        }
}

__global__ __launch_bounds__(512, 4) void vq_scan(const float* __restrict__ in,
                                                  const float* __restrict__ w,
                                                  const unsigned short* __restrict__ wpack,
                                                  const float* __restrict__ wsqf,
                                                  float* __restrict__ out,
                                                  unsigned short* __restrict__ pcounts,
                                                  double* __restrict__ ssep,
                                                  float* __restrict__ counts,
                                                  double* __restrict__ sse_acc,
                                                  const int amode) {
    __shared__ float wsqp[KCODES];              // 2048 B seeds
    __shared__ int idxbuf[512];                 // 2048 B
    __shared__ int hist[KCODES];                // 2048 B
    __shared__ double sred[8];

    const int tid = threadIdx.x;
    const int lane = tid & 63, wv = tid >> 6;   // wv in [0,8)
    const int col = lane & 15, quad = lane >> 4;
    const int ntok0 = blockIdx.x * 512;         // 256 blocks x 512 tokens

    wsqp[tid] = wsqf[tid];
    hist[tid] = 0;

    // ---- X gather + ah pack: 4 subs x 16 channels per thread (64 dwords;
    // each 64B line fully consumed by a 16-lane quad-group) ----
    const float* gbase = in + (ntok0 >> 12) * CHW + (ntok0 & 4095) + wv * 64 + col;
    short8 ah[4][2];
    float xsq = 0.f;
#pragma unroll
    for (int sub = 0; sub < 4; ++sub)
#pragma unroll
        for (int cc = 0; cc < 2; ++cc)
#pragma unroll
            for (int j0 = 0; j0 < 8; j0 += 4) {
                const float* gp = gbase + sub * 16 + (cc * 32 + quad * 8 + j0) * HW;
                const float x0 = gp[0 * HW], x1 = gp[1 * HW];
                const float x2 = gp[2 * HW], x3 = gp[3 * HW];
                ah[sub][cc][j0 + 0] = (short)f2bf(-2.0f * x0);
                ah[sub][cc][j0 + 1] = (short)f2bf(-2.0f * x1);
                ah[sub][cc][j0 + 2] = (short)f2bf(-2.0f * x2);
                ah[sub][cc][j0 + 3] = (short)f2bf(-2.0f * x3);
                xsq = fmaf(x0, x0, xsq); xsq = fmaf(x1, x1, xsq);
                xsq = fmaf(x2, x2, xsq); xsq = fmaf(x3, x3, xsq);
            }
    __syncthreads();  // B1: wsqp + hist ready (X is register-local)

    // ---- scan 32 tiles; B-fragments from global (L2-hot), 4-sub reuse ----
    const unsigned short* pb = wpack + quad * 128 + col * 8;
    unsigned runkey[4][4];
#pragma unroll
    for (int sub = 0; sub < 4; ++sub)
#pragma unroll
        for (int r = 0; r < 4; ++r) runkey[sub][r] = 0xFFFFFFFFu;

#pragma unroll 2
    for (int t = 0; t < 32; ++t) {
        const short8 b0 = *(const short8*)(pb + t * 1024);
        const short8 b1 = *(const short8*)(pb + t * 1024 + 512);
        const int code = t * 16 + col;
        const float seed = wsqp[code];
#pragma unroll
        for (int sub = 0; sub < 4; ++sub) {
            f32x4 acc = {seed, seed, seed, seed};
            acc = __builtin_amdgcn_mfma_f32_16x16x32_bf16(ah[sub][0], b0, acc, 0, 0, 0);
            acc = __builtin_amdgcn_mfma_f32_16x16x32_bf16(ah[sub][1], b1, acc, 0, 0, 0);
#pragma unroll
            for (int r = 0; r < 4; ++r) {
                const unsigned key = (__float_as_uint(acc[r]) << 9) | code;
                runkey[sub][r] = key < runkey[sub][r] ? key : runkey[sub][r];
            }
        }
    }

    // ---- cross-lane argmin over the 16 code-cols ----
#pragma unroll
    for (int s = 1; s < 16; s <<= 1)
#pragma unroll
        for (int sub = 0; sub < 4; ++sub)
#pragma unroll
            for (int r = 0; r < 4; ++r) {
                const unsigned o = __shfl_xor(runkey[sub][r], s, 64);
                runkey[sub][r] = o < runkey[sub][r] ? o : runkey[sub][r];
            }

    // d_best (exact from key) + publish indices (wave-local consumers)
    float dsum = 0.f;
    if (col == 0) {
#pragma unroll
        for (int sub = 0; sub < 4; ++sub)
#pragma unroll
            for (int r = 0; r < 4; ++r) {
                const unsigned key = runkey[sub][r];
                idxbuf[wv * 64 + sub * 16 + quad * 4 + r] = (int)(key & 511u);
                dsum += __uint_as_float((key >> 9) | 0x3F800000u) - 1.25f;
            }
    }
    float contrib = xsq + dsum;
#pragma unroll
    for (int off = 32; off > 0; off >>= 1) contrib += __shfl_down(contrib, off, 64);
    if (lane == 0) sred[wv] = (double)contrib;

    // per-wave histogram: all 64 lanes, one token each (wave-local idxbuf)
    atomicAdd(&hist[idxbuf[wv * 64 + lane]], 1);

    // ---- epilogue: out = w rows (L2-hot); 4 lanes/token, 4 passes ----
#pragma unroll
    for (int p = 0; p < 4; ++p) {
        const int tl = p * 16 + (lane >> 2), q = lane & 3;
        const int n = ntok0 + wv * 64 + tl;
        const int bidx = idxbuf[wv * 64 + tl];
        const float4* wr = (const float4*)(w + bidx * 64 + q * 16);
        float4* op = (float4*)(out + n * 64 + q * 16);
#pragma unroll
        for (int i = 0; i < 4; ++i) op[i] = wr[i];
    }
    __syncthreads();  // B2: hist + sred complete

    if (!amode) {
        pcounts[(blockIdx.x << 9) + tid] = (unsigned short)hist[tid];  // <=512
        if (tid == 0) {
            double s = sred[0];
#pragma unroll
            for (int i = 1; i < 8; ++i) s += sred[i];
            ssep[blockIdx.x] = s;
        }
    } else {  // fallback: atomics into tiny ws
        const int h = hist[tid];
        if (h) atomicAdd(&counts[tid], (float)h);
        if (tid == 0) {
            double s = sred[0];
#pragma unroll
            for (int i = 1; i < 8; ++i) s += sred[i];
            atomicAdd(sse_acc, s);
        }
    }
}

// parallel reduce over 256 rows: thread t owns 4 codes x 64 rows
__global__ __launch_bounds__(512) void vq_final_p(const unsigned short* __restrict__ pcounts,
                                                  const double* __restrict__ ssep,
                                                  float* __restrict__ out) {
    __shared__ float part[4][512];   // 8 KB: quarter x code
    __shared__ double red[512];
    __shared__ double sred[512];
    const int t = threadIdx.x;
    const int q = t >> 7, c4 = (t & 127) << 2;

    const u16x4* base = (const u16x4*)pcounts + (q << 13) + (c4 >> 2);
    float4 s = {0.f, 0.f, 0.f, 0.f};
#pragma unroll 16
    for (int b = 0; b < 64; ++b) {         // rows q*64 .. q*64+63
        const u16x4 v = base[b << 7];      // stride 512 ushorts = 128 u16x4
        s.x += (float)v[0]; s.y += (float)v[1];
        s.z += (float)v[2]; s.w += (float)v[3];
    }
    *(float4*)&part[q][c4] = s;
    sred[t] = (t < 256) ? ssep[t] : 0.0;
    __syncthreads();

    const float cnt = part[0][t] + part[1][t] + part[2][t] + part[3][t];
    const double p = (double)cnt / (double)NTOK;
    red[t] = p * log(p + 1e-10);
    __syncthreads();
#pragma unroll
    for (int st = 256; st > 0; st >>= 1) {
        if (t < st) { red[t] += red[t + st]; sred[t] += sred[t + st]; }
        __syncthreads();
    }
    if (t == 0) {
        out[NELEM] = (float)((sred[0] / (double)NELEM) * 1.25);
        out[NELEM + 1] = (float)exp(-red[0]);
    }
}

__global__ __launch_bounds__(512) void vq_final_a(const float* __restrict__ counts,
                                                  const double* __restrict__ sse_acc,
                                                  float* __restrict__ out) {
    __shared__ double red[512];
    const int k = threadIdx.x;
    const double p = (double)counts[k] / (double)NTOK;
    red[k] = p * log(p + 1e-10);
    __syncthreads();
#pragma unroll
    for (int st = 256; st > 0; st >>= 1) {
        if (k < st) red[k] += red[k + st];
        __syncthreads();
    }
    if (k == 0) {
        out[NELEM] = (float)((*sse_acc / (double)NELEM) * 1.25);
        out[NELEM + 1] = (float)exp(-red[0]);
    }
}

extern "C" void kernel_launch(void* const* d_in, const int* in_sizes, int n_in,
                              void* d_out, int out_size, void* d_ws, size_t ws_size,
                              hipStream_t stream) {
    const float* in = (const float*)d_in[0];
    const float* w = (const float*)d_in[1];
    float* out = (float*)d_out;
    char* ws = (char*)d_ws;

    const size_t WP = 0;                          // 64 KB wpack
    const size_t WQ = 65536;                      // +2 KB wsqf
    const size_t PC = WQ + 2048;                  // +256 KB pcounts u16[256][512]
    const size_t SSo = PC + (size_t)256 * 512 * 2;  // +2 KB ssep f64[256]
    const size_t need_full = SSo + 256 * 8;
    const size_t need_min = PC + 2048 + 8;        // counts + sse_acc

    unsigned short* wpack = (unsigned short*)(ws + WP);
    float* wsqf = (float*)(ws + WQ);

    if (ws_size >= need_full) {
        unsigned short* pcounts = (unsigned short*)(ws + PC);
        double* ssep = (double*)(ws + SSo);
        vq_pack<<<1, 512, 0, stream>>>(w, wpack, wsqf);
        vq_scan<<<256, 512, 0, stream>>>(in, w, wpack, wsqf, out, pcounts, ssep,
                                         nullptr, nullptr, 0);
        vq_final_p<<<1, 512, 0, stream>>>(pcounts, ssep, out);
    } else if (ws_size >= need_min) {  // fallback: atomic finals
        float* counts = (float*)(ws + PC);
        double* sse_acc = (double*)(ws + PC + 2048);
        (void)hipMemsetAsync(ws + PC, 0, 2056, stream);
        vq_pack<<<1, 512, 0, stream>>>(w, wpack, wsqf);
        vq_scan<<<256, 512, 0, stream>>>(in, w, wpack, wsqf, out, nullptr, nullptr,
                                         counts, sse_acc, 1);
        vq_final_a<<<1, 512, 0, stream>>>(counts, sse_acc, out);
    }
}